// Round 7
// baseline (2694.785 us; speedup 1.0000x reference)
//
#include <hip/hip_runtime.h>

// ---------------------------------------------------------------------------
// self_LSTM_sparse_attn — MI355X persistent-kernel, round 7.
//
// R6 post-mortem: 9.3us/step, VALU ~2.9us. Dominant hidden term: the weight
// stream — 1024 broadcast ds_read_b128/CU/step on the single LDS pipe
// (~4-5us). This round moves weights to the SCALAR pipe: wave-uniform rows
// read directly from global W_ih/W_hh (uniform addresses via readfirstlane)
// => s_load_dwordx8/16 + v_fma with SGPR operand. LDS weight staging gone.
// Tail is now fully replicated across all 4 waves (top-5 + c-state in
// registers per wave, bit-identical streams); each wave stores a disjoint
// share (mem / mseq / psum); exactly 2 barriers/step, one vmcnt drain (the
// implicit one in S2's __syncthreads) before the flag store.
//
// Carried invariants (R5/R6-verified): all cross-WG data write-once per
// step; cross-WG stores direct to LIC via sc0 sc1 (no fences anywhere);
// flag[g]=i+1 stored only after the drain of g's plane-(i+1) stores;
// per-wave producer wait: wave kq's inputs are written exactly by WGs
// [64kq,64kq+64), lane b polls flag[64kq+b].
// Algorithm (R2-R6-verified): s_h cancels in attention weights; w <=4-sparse;
// WG g owns h dims {2g,2g+1}; mem[i] == h_out(i-1); incremental top-5.
// ---------------------------------------------------------------------------

#define T_N 256
#define B_N 64
#define I_N 256
#define H_N 512
#define C_N 64
#define EPSF 1e-7f

typedef float v4f __attribute__((ext_vector_type(4)));
typedef float v2f __attribute__((ext_vector_type(2)));

// ws layout (float offsets). Packed layouts: [..][k4][b][u] u=k&3.
#define XT4_F   0u          // [T][64][64][4]    x packed          (4,194,304)
#define MEM4_F  4194304u    // [T+1][128][64][4] h_out history     (8,421,376)
#define MSEQ4_F 12615680u   // [T][128][64][4]   m_seq             (8,388,608)
#define PSUM4_F 21004288u   // [T+1][64][64][4]  score partials, write-once (4,210,688)
#define FCWT_F  25214976u   // [2H][C] fc_w transposed             (65,536)
#define FLAG_F  25280512u   // [256] arrival flags, packed u32     (256)
#define TOT_F   25280768u

__device__ __forceinline__ float sigf(float x) { return 1.0f / (1.0f + expf(-x)); }

// direct-to-LIC (coherence point) ops — no fences needed anywhere.
__device__ __forceinline__ void st_lic_f32(float* p, float v) {
  asm volatile("global_store_dword %0, %1, off sc0 sc1" :: "v"(p), "v"(v) : "memory");
}
__device__ __forceinline__ void st_lic_f32x2(float* p, v2f v) {
  asm volatile("global_store_dwordx2 %0, %1, off sc0 sc1" :: "v"(p), "v"(v) : "memory");
}
__device__ __forceinline__ void st_lic_u32(unsigned* p, unsigned v) {
  asm volatile("global_store_dword %0, %1, off sc0 sc1" :: "v"(p), "v"(v) : "memory");
}
__device__ __forceinline__ unsigned ld_lic_u32(const unsigned* p) {
  unsigned r;
  asm volatile("global_load_dword %0, %1, off sc0 sc1\n\ts_waitcnt vmcnt(0)"
               : "=v"(r) : "v"(p) : "memory");
  return r;
}

__device__ __forceinline__ void ins5(float s, int t,
                                     float& v0, float& v1, float& v2, float& v3, float& v4,
                                     int& j0, int& j1, int& j2, int& j3) {
  if (s > v4) {
    if (s > v0)      { v4=v3; v3=v2; j3=j2; v2=v1; j2=j1; v1=v0; j1=j0; v0=s; j0=t; }
    else if (s > v1) { v4=v3; v3=v2; j3=j2; v2=v1; j2=j1; v1=s; j1=t; }
    else if (s > v2) { v4=v3; v3=v2; j3=j2; v2=s; j2=t; }
    else if (s > v3) { v4=v3; v3=s; j3=t; }
    else             { v4=s; }
  }
}

__global__ void poison_k(float* out, int n) {
  int i = blockIdx.x * 256 + threadIdx.x;
  if (i < n) out[i] = __int_as_float(0x7fc00000);
}

// blocks 0..1023: x -> xT4 packed; blocks 1024..1039: fc_w -> fcwT[d][c]
__global__ void init_k(const float* __restrict__ x, const float* __restrict__ fc_w,
                       float* __restrict__ ws) {
  __shared__ float tile[64][65];
  const int blk = blockIdx.x, tid = threadIdx.x;
  if (blk < 1024) {
    const int t = blk >> 2, k0 = (blk & 3) * 64;
    for (int u = tid; u < 4096; u += 256) {
      int bb = u >> 6, kk = u & 63;
      tile[kk][bb] = x[((unsigned)t * 64u + bb) * 256u + k0 + kk];
    }
    __syncthreads();
    for (int u = tid; u < 4096; u += 256) {
      int kk = u >> 6, bb = u & 63;
      int k = k0 + kk;
      ws[XT4_F + (unsigned)t * 16384u + (unsigned)(k >> 2) * 256u
         + (unsigned)bb * 4u + (unsigned)(k & 3)] = tile[kk][bb];
    }
  } else {
    const int d0 = (blk - 1024) * 64;
    for (int u = tid; u < 4096; u += 256) {
      int cc = u >> 6, dd = u & 63;
      tile[dd][cc] = fc_w[(unsigned)cc * 1024u + d0 + dd];
    }
    __syncthreads();
    for (int u = tid; u < 4096; u += 256) {
      int dd = u >> 6, cc = u & 63;
      ws[FCWT_F + (unsigned)(d0 + dd) * 64u + cc] = tile[dd][cc];
    }
  }
}

__launch_bounds__(256, 1)
__global__ void lstm_main(const float* __restrict__ W_ih, const float* __restrict__ W_hh,
                          const float* __restrict__ b_ih, const float* __restrict__ b_hh,
                          const float* __restrict__ w_t, float* __restrict__ ws) {
  __shared__ float red[4][8][B_N];    // 8 KB gate partials per k-quarter
  __shared__ float psum[4][B_N];      // 1 KB

  const int g = blockIdx.x;
  const int tid = threadIdx.x;
  const int b = tid & 63;
  const int kqu = __builtin_amdgcn_readfirstlane(tid >> 6);  // provably uniform wave id

  unsigned int* flags = (unsigned int*)(ws + FLAG_F);

  // wave-uniform weight row pointers (SGPR) — rows stream via s_load each step
  const float* Wh_r[8];
  const float* Wx_r[8];
  float bias_r[8];
  #pragma unroll
  for (int r = 0; r < 8; ++r) {
    int grow = (r >> 1) * H_N + 2 * g + (r & 1);   // r = gate*2 + jj
    Wh_r[r] = W_hh + (size_t)grow * H_N + kqu * 128;
    Wx_r[r] = W_ih + (size_t)grow * I_N + kqu * 64;
    bias_r[r] = b_ih[grow] + b_hh[grow];
  }
  const float wt20 = w_t[H_N + 2 * g];
  const float wt21 = w_t[H_N + 2 * g + 1];

  // per-wave replicated state (bit-identical streams across waves)
  float cs0 = 0.0f, cs1 = 0.0f;                       // LSTM c-state, dims 2g/2g+1
  float v0 = -3e38f, v1 = -3e38f, v2 = -3e38f, v3 = -3e38f, v4 = -3e38f;
  int j0 = 0, j1 = 0, j2 = 0, j3 = 0;
  float mn = 3e38f;

  const unsigned hoff0 = (unsigned)(g >> 1) * 256u + (unsigned)b * 4u + (unsigned)((g & 1) * 2);

  // prologue: x-part of step 0's matvec (weights via scalar pipe)
  float xacc[8];
  #pragma unroll
  for (int r = 0; r < 8; ++r) xacc[r] = 0.0f;
  {
    const v4f* xp = (const v4f*)(ws + XT4_F) + (unsigned)(kqu * 16) * 64u + b;
    v4f xv[16];
    #pragma unroll
    for (int j = 0; j < 16; ++j) xv[j] = xp[j * 64];
    #pragma unroll
    for (int j = 0; j < 16; ++j) {
      #pragma unroll
      for (int u = 0; u < 4; ++u) {
        float v = xv[j][u];
        #pragma unroll
        for (int r = 0; r < 8; ++r) xacc[r] += v * Wx_r[r][4 * j + u];
      }
    }
  }

  for (int i = 0; i < T_N; ++i) {
    // ---- S0: per-wave producer wait (producers of this wave's quarter) ----
    if (i > 0) {
      const unsigned* fp = flags + ((kqu << 6) | b);
      while (ld_lic_u32(fp) < (unsigned)i) __builtin_amdgcn_s_sleep(1);
    }

    // ---- Phase A: batched vector loads; weights stream on scalar pipe ----
    v4f pv[16];
    {
      const v4f* pp = (const v4f*)(ws + PSUM4_F) + (unsigned)i * 4096u
                      + (unsigned)(kqu * 16) * 64u + b;
      #pragma unroll
      for (int j = 0; j < 16; ++j) pv[j] = pp[j * 64];
    }
    v4f hv[32];
    {
      const v4f* hp = (const v4f*)(ws + MEM4_F) + (unsigned)i * 8192u
                      + (unsigned)(kqu * 32) * 64u + b;  // mem[i] == h_out(i-1)
      #pragma unroll
      for (int j = 0; j < 32; ++j) hv[j] = hp[j * 64];
    }
    float ps = 0.0f;
    #pragma unroll
    for (int j = 0; j < 16; ++j) ps += (pv[j][0] + pv[j][1]) + (pv[j][2] + pv[j][3]);
    psum[kqu][b] = ps;

    float acc[8];
    #pragma unroll
    for (int r = 0; r < 8; ++r) acc[r] = xacc[r];
    #pragma unroll
    for (int j = 0; j < 32; ++j) {
      #pragma unroll
      for (int u = 0; u < 4; ++u) {
        float v = hv[j][u];
        #pragma unroll
        for (int r = 0; r < 8; ++r) acc[r] += v * Wh_r[r][4 * j + u];
      }
    }
    #pragma unroll
    for (int r = 0; r < 8; ++r) red[kqu][r][b] = acc[r];
    __syncthreads();  // S1

    // ---- replicated tail (all 4 waves, bit-identical) ----
    float sc = psum[0][b] + psum[1][b] + psum[2][b] + psum[3][b];
    ins5(sc, i, v0, v1, v2, v3, v4, j0, j1, j2, j3);
    mn = fminf(mn, sc);
    float delta = ((i + 1) <= 5 ? mn : v4) + EPSF;
    float w0 = fmaxf(v0 - delta, 0.0f);
    float w1 = fmaxf(v1 - delta, 0.0f);
    float w2 = fmaxf(v2 - delta, 0.0f);
    float w3 = fmaxf(v3 - delta, 0.0f);
    float inv = 1.0f / (w0 + w1 + w2 + w3 + EPSF);
    w0 *= inv; w1 *= inv; w2 *= inv; w3 *= inv;

    // sparse gather (dims 2g,2g+1 adjacent -> dwordx2), issued before gate math
    const v2f* mb2 = (const v2f*)(ws + MEM4_F + hoff0);
    v2f q0 = mb2[(unsigned)j0 * 16384u];
    v2f q1 = mb2[(unsigned)j1 * 16384u];
    v2f q2 = mb2[(unsigned)j2 * 16384u];
    v2f q3 = mb2[(unsigned)j3 * 16384u];

    float G[8];
    #pragma unroll
    for (int r = 0; r < 8; ++r)
      G[r] = red[0][r][b] + red[1][r][b] + red[2][r][b] + red[3][r][b] + bias_r[r];

    float cn0 = sigf(G[2]) * cs0 + sigf(G[0]) * tanhf(G[4]);
    float hn0 = sigf(G[6]) * tanhf(cn0);
    float cn1 = sigf(G[3]) * cs1 + sigf(G[1]) * tanhf(G[5]);
    float hn1 = sigf(G[7]) * tanhf(cn1);
    cs0 = cn0; cs1 = cn1;

    float m0 = w0 * q0[0] + w1 * q1[0] + w2 * q2[0] + w3 * q3[0];
    float m1 = w0 * q0[1] + w1 * q1[1] + w2 * q2[1] + w3 * q3[1];
    float ho0 = hn0 + m0, ho1 = hn1 + m1;

    // disjoint store shares per wave
    if (kqu == 0) {
      v2f hov; hov[0] = ho0; hov[1] = ho1;
      st_lic_f32x2(ws + MEM4_F + (unsigned)(i + 1) * 32768u + hoff0, hov);
    } else if (kqu == 1) {
      ws[MSEQ4_F + (unsigned)i * 32768u + hoff0]      = m0;   // out_gemm-only
      ws[MSEQ4_F + (unsigned)i * 32768u + hoff0 + 1u] = m1;
    } else if (kqu == 2) {
      st_lic_f32(ws + PSUM4_F + (unsigned)(i + 1) * 16384u + (unsigned)(g >> 2) * 256u
                 + (unsigned)b * 4u + (unsigned)(g & 3),
                 tanhf(ho0) * wt20 + tanhf(ho1) * wt21);
    }
    __syncthreads();  // S2 — implicit per-wave vmcnt(0): all stores at LIC
    if (tid == 0) st_lic_u32(&flags[g], (unsigned)(i + 1));

    // ---- overlap: x-part of NEXT step's matvec (static xT4) ----
    if (i + 1 < T_N) {
      const v4f* xp = (const v4f*)(ws + XT4_F) + (unsigned)(i + 1) * 4096u
                      + (unsigned)(kqu * 16) * 64u + b;
      v4f xv[16];
      #pragma unroll
      for (int j = 0; j < 16; ++j) xv[j] = xp[j * 64];
      #pragma unroll
      for (int r = 0; r < 8; ++r) xacc[r] = 0.0f;
      #pragma unroll
      for (int j = 0; j < 16; ++j) {
        #pragma unroll
        for (int u = 0; u < 4; ++u) {
          float v = xv[j][u];
          #pragma unroll
          for (int r = 0; r < 8; ++r) xacc[r] += v * Wx_r[r][4 * j + u];
        }
      }
    }
  }
}

// out[t,b,c] = sum_d feats[t,d,b]*fcwT[d,c] + fc_b[c];
// feats h-half == mem4[t+1], m-half == mseq4[t] (packed [k4][b][4]).
__launch_bounds__(256, 4)
__global__ void out_gemm(const float* __restrict__ ws, const float* __restrict__ fc_b,
                         float* __restrict__ out) {
  __shared__ float fw[64][16];
  const int t = blockIdx.x >> 2, cg = blockIdx.x & 3;
  const int tid = threadIdx.x, b = tid & 63, cs = (tid >> 6) * 4;
  float acc[4] = {0.0f, 0.0f, 0.0f, 0.0f};
  const v4f* hsrc = (const v4f*)(ws + MEM4_F) + (unsigned)(t + 1) * 8192u + b;
  const v4f* msrc = (const v4f*)(ws + MSEQ4_F) + (unsigned)t * 8192u + b;
  for (int half = 0; half < 2; ++half) {
    const v4f* src = half ? msrc : hsrc;
    for (int dt = 0; dt < 512; dt += 64) {
      __syncthreads();
      for (int u = tid; u < 1024; u += 256) {
        int dd = u >> 4, cc = u & 15;
        fw[dd][cc] = ws[FCWT_F + (unsigned)(half * 512 + dt + dd) * 64u + cg * 16 + cc];
      }
      __syncthreads();
      #pragma unroll 4
      for (int j = 0; j < 16; ++j) {
        v4f f4 = src[(unsigned)(dt / 4 + j) * 64u];
        #pragma unroll
        for (int u = 0; u < 4; ++u) {
          float f = f4[u];
          const float* wr = &fw[4 * j + u][cs];
          #pragma unroll
          for (int c4 = 0; c4 < 4; ++c4) acc[c4] += f * wr[c4];
        }
      }
    }
  }
  float* op = out + ((unsigned)t * 64u + b) * 64u + cg * 16 + cs;
  #pragma unroll
  for (int c4 = 0; c4 < 4; ++c4) op[c4] = acc[c4] + fc_b[cg * 16 + cs + c4];
}

extern "C" void kernel_launch(void* const* d_in, const int* in_sizes, int n_in,
                              void* d_out, int out_size, void* d_ws, size_t ws_size,
                              hipStream_t stream) {
  const float* x    = (const float*)d_in[0];
  const float* W_ih = (const float*)d_in[1];
  const float* W_hh = (const float*)d_in[2];
  const float* b_ih = (const float*)d_in[3];
  const float* b_hh = (const float*)d_in[4];
  const float* w_t  = (const float*)d_in[5];
  const float* fc_w = (const float*)d_in[6];
  const float* fc_b = (const float*)d_in[7];
  float* out = (float*)d_out;
  float* ws  = (float*)d_ws;

  if (ws_size < (size_t)TOT_F * 4u) {
    poison_k<<<(out_size + 255) / 256, 256, 0, stream>>>(out, out_size);
    return;
  }

  hipMemsetAsync(ws + MEM4_F, 0, (size_t)32768u * 4u, stream);     // mem[0] = 0
  hipMemsetAsync(ws + PSUM4_F, 0, (size_t)16384u * 4u, stream);    // psum plane 0
  hipMemsetAsync(ws + FLAG_F, 0, 256u * 4u, stream);               // flags

  init_k<<<1040, 256, 0, stream>>>(x, fc_w, ws);
  lstm_main<<<256, 256, 0, stream>>>(W_ih, W_hh, b_ih, b_hh, w_t, ws);
  out_gemm<<<1024, 256, 0, stream>>>(ws, fc_b, out);
}

// Round 8
// 1691.917 us; speedup vs baseline: 1.5927x; 1.5927x over previous
//
#include <hip/hip_runtime.h>

// ---------------------------------------------------------------------------
// self_LSTM_sparse_attn — MI355X persistent-kernel, round 8.
//
// R7 falsified the LDS-pipe theory (conflicts->0, time +11%): with only
// 1 wave/SIMD, all latencies are bare. This round: 512-thread WGs = 8 waves
// = 2 waves/SIMD at IDENTICAL per-CU traffic (same 256 WGs, same ownership).
// Each wave takes a k-eighth; producer sets coincide: wave kq's psum slots
// [8kq,8kq+8) and mem dims [64kq,64kq+64) are both written by WGs
// [32kq,32kq+32) -> lane polls flag[32kq+(b&31)]. Weights back in LDS
// (R6-proven; broadcast ds_reads are conflict-free); red exchange paired
// as float2.
//
// Carried invariants (R5-R7-verified): cross-WG data write-once per step;
// cross-WG stores direct to LIC via sc0 sc1 (no fences anywhere); flag[g]
// stored only after the __syncthreads vmcnt drain of g's plane stores;
// gather touches only this WG's own dims (self-written, LIC-then-L2).
// Algorithm (R2-R7-verified): s_h cancels in attention weights; w <=4-sparse;
// WG g owns h dims {2g,2g+1}; mem[i] == h_out(i-1); incremental top-5 in
// registers, replicated per wave (bit-identical streams).
// ---------------------------------------------------------------------------

#define T_N 256
#define B_N 64
#define I_N 256
#define H_N 512
#define C_N 64
#define EPSF 1e-7f

typedef float v4f __attribute__((ext_vector_type(4)));
typedef float v2f __attribute__((ext_vector_type(2)));

// ws layout (float offsets). Packed layouts: [..][k4][b][u] u=k&3.
#define XT4_F   0u          // [T][64][64][4]    x packed          (4,194,304)
#define MEM4_F  4194304u    // [T+1][128][64][4] h_out history     (8,421,376)
#define MSEQ4_F 12615680u   // [T][128][64][4]   m_seq             (8,388,608)
#define PSUM4_F 21004288u   // [T+1][64][64][4]  score partials, write-once (4,210,688)
#define FCWT_F  25214976u   // [2H][C] fc_w transposed             (65,536)
#define FLAG_F  25280512u   // [256] arrival flags, packed u32     (256)
#define TOT_F   25280768u

__device__ __forceinline__ float sigf(float x) { return 1.0f / (1.0f + expf(-x)); }

// direct-to-LIC (coherence point) ops — no fences needed anywhere.
__device__ __forceinline__ void st_lic_f32(float* p, float v) {
  asm volatile("global_store_dword %0, %1, off sc0 sc1" :: "v"(p), "v"(v) : "memory");
}
__device__ __forceinline__ void st_lic_f32x2(float* p, v2f v) {
  asm volatile("global_store_dwordx2 %0, %1, off sc0 sc1" :: "v"(p), "v"(v) : "memory");
}
__device__ __forceinline__ void st_lic_u32(unsigned* p, unsigned v) {
  asm volatile("global_store_dword %0, %1, off sc0 sc1" :: "v"(p), "v"(v) : "memory");
}
__device__ __forceinline__ unsigned ld_lic_u32(const unsigned* p) {
  unsigned r;
  asm volatile("global_load_dword %0, %1, off sc0 sc1\n\ts_waitcnt vmcnt(0)"
               : "=v"(r) : "v"(p) : "memory");
  return r;
}

__device__ __forceinline__ void ins5(float s, int t,
                                     float& v0, float& v1, float& v2, float& v3, float& v4,
                                     int& j0, int& j1, int& j2, int& j3) {
  if (s > v4) {
    if (s > v0)      { v4=v3; v3=v2; j3=j2; v2=v1; j2=j1; v1=v0; j1=j0; v0=s; j0=t; }
    else if (s > v1) { v4=v3; v3=v2; j3=j2; v2=v1; j2=j1; v1=s; j1=t; }
    else if (s > v2) { v4=v3; v3=v2; j3=j2; v2=s; j2=t; }
    else if (s > v3) { v4=v3; v3=s; j3=t; }
    else             { v4=s; }
  }
}

__global__ void poison_k(float* out, int n) {
  int i = blockIdx.x * 256 + threadIdx.x;
  if (i < n) out[i] = __int_as_float(0x7fc00000);
}

// blocks 0..1023: x -> xT4 packed; blocks 1024..1039: fc_w -> fcwT[d][c]
__global__ void init_k(const float* __restrict__ x, const float* __restrict__ fc_w,
                       float* __restrict__ ws) {
  __shared__ float tile[64][65];
  const int blk = blockIdx.x, tid = threadIdx.x;
  if (blk < 1024) {
    const int t = blk >> 2, k0 = (blk & 3) * 64;
    for (int u = tid; u < 4096; u += 256) {
      int bb = u >> 6, kk = u & 63;
      tile[kk][bb] = x[((unsigned)t * 64u + bb) * 256u + k0 + kk];
    }
    __syncthreads();
    for (int u = tid; u < 4096; u += 256) {
      int kk = u >> 6, bb = u & 63;
      int k = k0 + kk;
      ws[XT4_F + (unsigned)t * 16384u + (unsigned)(k >> 2) * 256u
         + (unsigned)bb * 4u + (unsigned)(k & 3)] = tile[kk][bb];
    }
  } else {
    const int d0 = (blk - 1024) * 64;
    for (int u = tid; u < 4096; u += 256) {
      int cc = u >> 6, dd = u & 63;
      tile[dd][cc] = fc_w[(unsigned)cc * 1024u + d0 + dd];
    }
    __syncthreads();
    for (int u = tid; u < 4096; u += 256) {
      int dd = u >> 6, cc = u & 63;
      ws[FCWT_F + (unsigned)(d0 + dd) * 64u + cc] = tile[dd][cc];
    }
  }
}

__launch_bounds__(512, 1)
__global__ void lstm_main(const float* __restrict__ W_ih, const float* __restrict__ W_hh,
                          const float* __restrict__ b_ih, const float* __restrict__ b_hh,
                          const float* __restrict__ w_t, float* __restrict__ ws) {
  __shared__ float Wx[I_N][8];           // 8 KB  weight rows, LDS-resident
  __shared__ float Wh[H_N][8];           // 16 KB
  __shared__ float red2[8][4][B_N][2];   // 16 KB gate partials (row pairs)
  __shared__ float psum[8][B_N];         // 2 KB

  const int g = blockIdx.x;
  const int tid = threadIdx.x;
  const int b = tid & 63;
  const int kqu = __builtin_amdgcn_readfirstlane(tid >> 6);  // wave id 0..7

  unsigned int* flags = (unsigned int*)(ws + FLAG_F);

  // stage weights (resident all steps)
  for (int idx = tid; idx < 8 * I_N; idx += 512) {
    int rr = idx >> 8, k = idx & (I_N - 1);
    int grow = (rr >> 1) * H_N + 2 * g + (rr & 1);   // rr = gate*2 + jj
    Wx[k][rr] = W_ih[grow * I_N + k];
  }
  for (int idx = tid; idx < 8 * H_N; idx += 512) {
    int rr = idx >> 9, k = idx & (H_N - 1);
    int grow = (rr >> 1) * H_N + 2 * g + (rr & 1);
    Wh[k][rr] = W_hh[grow * H_N + k];
  }
  float bias_r[8];
  #pragma unroll
  for (int r = 0; r < 8; ++r) {
    int grow = (r >> 1) * H_N + 2 * g + (r & 1);
    bias_r[r] = b_ih[grow] + b_hh[grow];
  }
  const float wt20 = w_t[H_N + 2 * g];
  const float wt21 = w_t[H_N + 2 * g + 1];
  __syncthreads();

  // per-wave replicated state (bit-identical streams across waves)
  float cs0 = 0.0f, cs1 = 0.0f;
  float v0 = -3e38f, v1 = -3e38f, v2 = -3e38f, v3 = -3e38f, v4 = -3e38f;
  int j0 = 0, j1 = 0, j2 = 0, j3 = 0;
  float mn = 3e38f;

  const unsigned hoff0 = (unsigned)(g >> 1) * 256u + (unsigned)b * 4u + (unsigned)((g & 1) * 2);

  // prologue: x-part of step 0's matvec (k-eighth per wave)
  float xacc[8];
  #pragma unroll
  for (int r = 0; r < 8; ++r) xacc[r] = 0.0f;
  {
    const v4f* xp = (const v4f*)(ws + XT4_F) + (unsigned)(kqu * 8) * 64u + b;
    v4f xv[8];
    #pragma unroll
    for (int j = 0; j < 8; ++j) xv[j] = xp[j * 64];
    #pragma unroll
    for (int j = 0; j < 8; ++j) {
      #pragma unroll
      for (int u = 0; u < 4; ++u) {
        float v = xv[j][u];
        const float* wr = &Wx[kqu * 32 + 4 * j + u][0];
        #pragma unroll
        for (int r = 0; r < 8; ++r) xacc[r] += v * wr[r];
      }
    }
  }

  for (int i = 0; i < T_N; ++i) {
    // ---- S0: per-wave producer wait. Wave kqu's psum slots AND mem dims
    // are both written exactly by WGs [32kqu, 32kqu+32). ----
    if (i > 0) {
      const unsigned* fp = flags + (kqu * 32 + (b & 31));
      while (ld_lic_u32(fp) < (unsigned)i) __builtin_amdgcn_s_sleep(1);
    }

    // ---- Phase A: batched vector loads; weights broadcast from LDS ----
    v4f pv[8];
    {
      const v4f* pp = (const v4f*)(ws + PSUM4_F) + (unsigned)i * 4096u
                      + (unsigned)(kqu * 8) * 64u + b;
      #pragma unroll
      for (int j = 0; j < 8; ++j) pv[j] = pp[j * 64];
    }
    v4f hv[16];
    {
      const v4f* hp = (const v4f*)(ws + MEM4_F) + (unsigned)i * 8192u
                      + (unsigned)(kqu * 16) * 64u + b;  // mem[i] == h_out(i-1)
      #pragma unroll
      for (int j = 0; j < 16; ++j) hv[j] = hp[j * 64];
    }
    float ps = 0.0f;
    #pragma unroll
    for (int j = 0; j < 8; ++j) ps += (pv[j][0] + pv[j][1]) + (pv[j][2] + pv[j][3]);
    psum[kqu][b] = ps;

    float acc[8];
    #pragma unroll
    for (int r = 0; r < 8; ++r) acc[r] = xacc[r];
    #pragma unroll
    for (int j = 0; j < 16; ++j) {
      #pragma unroll
      for (int u = 0; u < 4; ++u) {
        float v = hv[j][u];
        const float* wr = &Wh[kqu * 64 + 4 * j + u][0];
        #pragma unroll
        for (int r = 0; r < 8; ++r) acc[r] += v * wr[r];
      }
    }
    #pragma unroll
    for (int p = 0; p < 4; ++p) {
      red2[kqu][p][b][0] = acc[2 * p];
      red2[kqu][p][b][1] = acc[2 * p + 1];
    }
    __syncthreads();  // S1

    // ---- replicated tail (all 8 waves, bit-identical) ----
    float sc = ((psum[0][b] + psum[1][b]) + (psum[2][b] + psum[3][b]))
             + ((psum[4][b] + psum[5][b]) + (psum[6][b] + psum[7][b]));
    ins5(sc, i, v0, v1, v2, v3, v4, j0, j1, j2, j3);
    mn = fminf(mn, sc);
    float delta = ((i + 1) <= 5 ? mn : v4) + EPSF;
    float w0 = fmaxf(v0 - delta, 0.0f);
    float w1 = fmaxf(v1 - delta, 0.0f);
    float w2 = fmaxf(v2 - delta, 0.0f);
    float w3 = fmaxf(v3 - delta, 0.0f);
    float inv = 1.0f / (w0 + w1 + w2 + w3 + EPSF);
    w0 *= inv; w1 *= inv; w2 *= inv; w3 *= inv;

    // sparse gather (this WG's own dims; old planes -> L2-cached after first)
    const v2f* mb2 = (const v2f*)(ws + MEM4_F + hoff0);
    v2f q0 = mb2[(unsigned)j0 * 16384u];
    v2f q1 = mb2[(unsigned)j1 * 16384u];
    v2f q2 = mb2[(unsigned)j2 * 16384u];
    v2f q3 = mb2[(unsigned)j3 * 16384u];

    float G[8];
    #pragma unroll
    for (int r = 0; r < 8; ++r) G[r] = bias_r[r];
    #pragma unroll
    for (int q = 0; q < 8; ++q) {
      #pragma unroll
      for (int p = 0; p < 4; ++p) {
        G[2 * p]     += red2[q][p][b][0];
        G[2 * p + 1] += red2[q][p][b][1];
      }
    }

    float cn0 = sigf(G[2]) * cs0 + sigf(G[0]) * tanhf(G[4]);
    float hn0 = sigf(G[6]) * tanhf(cn0);
    float cn1 = sigf(G[3]) * cs1 + sigf(G[1]) * tanhf(G[5]);
    float hn1 = sigf(G[7]) * tanhf(cn1);
    cs0 = cn0; cs1 = cn1;

    float m0 = w0 * q0[0] + w1 * q1[0] + w2 * q2[0] + w3 * q3[0];
    float m1 = w0 * q0[1] + w1 * q1[1] + w2 * q2[1] + w3 * q3[1];
    float ho0 = hn0 + m0, ho1 = hn1 + m1;

    // disjoint store shares per wave
    if (kqu == 0) {
      v2f hov; hov[0] = ho0; hov[1] = ho1;
      st_lic_f32x2(ws + MEM4_F + (unsigned)(i + 1) * 32768u + hoff0, hov);
    } else if (kqu == 1) {
      v2f mv; mv[0] = m0; mv[1] = m1;
      *(v2f*)(ws + MSEQ4_F + (unsigned)i * 32768u + hoff0) = mv;  // out_gemm-only
    } else if (kqu == 2) {
      st_lic_f32(ws + PSUM4_F + (unsigned)(i + 1) * 16384u + (unsigned)(g >> 2) * 256u
                 + (unsigned)b * 4u + (unsigned)(g & 3),
                 tanhf(ho0) * wt20 + tanhf(ho1) * wt21);
    }
    __syncthreads();  // S2 — per-wave vmcnt(0) drain: all shares at LIC
    if (tid == 0) st_lic_u32(&flags[g], (unsigned)(i + 1));

    // ---- overlap: x-part of NEXT step's matvec (static xT4) ----
    if (i + 1 < T_N) {
      const v4f* xp = (const v4f*)(ws + XT4_F) + (unsigned)(i + 1) * 4096u
                      + (unsigned)(kqu * 8) * 64u + b;
      v4f xv[8];
      #pragma unroll
      for (int j = 0; j < 8; ++j) xv[j] = xp[j * 64];
      #pragma unroll
      for (int r = 0; r < 8; ++r) xacc[r] = 0.0f;
      #pragma unroll
      for (int j = 0; j < 8; ++j) {
        #pragma unroll
        for (int u = 0; u < 4; ++u) {
          float v = xv[j][u];
          const float* wr = &Wx[kqu * 32 + 4 * j + u][0];
          #pragma unroll
          for (int r = 0; r < 8; ++r) xacc[r] += v * wr[r];
        }
      }
    }
  }
}

// out[t,b,c] = sum_d feats[t,d,b]*fcwT[d,c] + fc_b[c];
// feats h-half == mem4[t+1], m-half == mseq4[t] (packed [k4][b][4]).
__launch_bounds__(256, 4)
__global__ void out_gemm(const float* __restrict__ ws, const float* __restrict__ fc_b,
                         float* __restrict__ out) {
  __shared__ float fw[64][16];
  const int t = blockIdx.x >> 2, cg = blockIdx.x & 3;
  const int tid = threadIdx.x, b = tid & 63, cs = (tid >> 6) * 4;
  float acc[4] = {0.0f, 0.0f, 0.0f, 0.0f};
  const v4f* hsrc = (const v4f*)(ws + MEM4_F) + (unsigned)(t + 1) * 8192u + b;
  const v4f* msrc = (const v4f*)(ws + MSEQ4_F) + (unsigned)t * 8192u + b;
  for (int half = 0; half < 2; ++half) {
    const v4f* src = half ? msrc : hsrc;
    for (int dt = 0; dt < 512; dt += 64) {
      __syncthreads();
      for (int u = tid; u < 1024; u += 256) {
        int dd = u >> 4, cc = u & 15;
        fw[dd][cc] = ws[FCWT_F + (unsigned)(half * 512 + dt + dd) * 64u + cg * 16 + cc];
      }
      __syncthreads();
      #pragma unroll 4
      for (int j = 0; j < 16; ++j) {
        v4f f4 = src[(unsigned)(dt / 4 + j) * 64u];
        #pragma unroll
        for (int u = 0; u < 4; ++u) {
          float f = f4[u];
          const float* wr = &fw[4 * j + u][cs];
          #pragma unroll
          for (int c4 = 0; c4 < 4; ++c4) acc[c4] += f * wr[c4];
        }
      }
    }
  }
  float* op = out + ((unsigned)t * 64u + b) * 64u + cg * 16 + cs;
  #pragma unroll
  for (int c4 = 0; c4 < 4; ++c4) op[c4] = acc[c4] + fc_b[cg * 16 + cs + c4];
}

extern "C" void kernel_launch(void* const* d_in, const int* in_sizes, int n_in,
                              void* d_out, int out_size, void* d_ws, size_t ws_size,
                              hipStream_t stream) {
  const float* x    = (const float*)d_in[0];
  const float* W_ih = (const float*)d_in[1];
  const float* W_hh = (const float*)d_in[2];
  const float* b_ih = (const float*)d_in[3];
  const float* b_hh = (const float*)d_in[4];
  const float* w_t  = (const float*)d_in[5];
  const float* fc_w = (const float*)d_in[6];
  const float* fc_b = (const float*)d_in[7];
  float* out = (float*)d_out;
  float* ws  = (float*)d_ws;

  if (ws_size < (size_t)TOT_F * 4u) {
    poison_k<<<(out_size + 255) / 256, 256, 0, stream>>>(out, out_size);
    return;
  }

  hipMemsetAsync(ws + MEM4_F, 0, (size_t)32768u * 4u, stream);     // mem[0] = 0
  hipMemsetAsync(ws + PSUM4_F, 0, (size_t)16384u * 4u, stream);    // psum plane 0
  hipMemsetAsync(ws + FLAG_F, 0, 256u * 4u, stream);               // flags

  init_k<<<1040, 256, 0, stream>>>(x, fc_w, ws);
  lstm_main<<<256, 512, 0, stream>>>(W_ih, W_hh, b_ih, b_hh, w_t, ws);
  out_gemm<<<1024, 256, 0, stream>>>(ws, fc_b, out);
}